// Round 3
// baseline (245.896 us; speedup 1.0000x reference)
//
#include <hip/hip_runtime.h>
#include <math.h>

// Problem constants (fixed by the reference): Q=4096 queries, N=65536 train, D=32.
#define QN 4096
#define NN 65536
#define DD 32

#define GRID_X 8        // query blocks: 8 * 512 = 4096
#define GRID_Y 256      // train strips
#define STRIP  256      // train points per strip
#define ITERS  16       // STRIP / 16
#define NBLK   (GRID_X * GRID_Y)

typedef __attribute__((ext_vector_type(8))) _Float16 half8;
typedef __attribute__((ext_vector_type(4))) _Float16 half4v;
typedef __attribute__((ext_vector_type(4))) float floatx4;

#define LOG2E 1.4426950408889634f
#define HALF_D_LOG_2PI 29.40603306254953f   // 16 * ln(2*pi)

// ---------------------------------------------------------------------------
// Workspace layout (bytes):
//   Xh   @ 0        : QN*DD*2 = 262144   (_Float16, X * log2(e))
//   Xth  @ 262144   : NN*DD*2 = 4194304  (_Float16, X_train unscaled)
//   c    @ 4456448  : NN*4    = 262144   (w_j * exp(-||y_j||^2/2))
//   qn   @ 4718592  : QN*4    = 16384    (||x_i||^2 / 2, nat units)
//   S    @ 4734976  : QN*4    = 16384    (zeroed by prep_all)
//   swp  @ 4751360  : 64*4    = 256      (per-block partial sums of w)
//   done @ 4751616  : 4                  (block-completion counter)
// ---------------------------------------------------------------------------

// Fused prep: blocks [0,128) convert X (+ zero S/done), [128,2176) convert
// X_train + c, [2176,2240) reduce sum(w) into per-block partials.
__global__ __launch_bounds__(256) void prep_all(
    const float* __restrict__ X, const float* __restrict__ Xt,
    const float* __restrict__ w, _Float16* __restrict__ Xh,
    float* __restrict__ qn, _Float16* __restrict__ Xth,
    float* __restrict__ c, float* __restrict__ S,
    float* __restrict__ swp, unsigned* __restrict__ done) {
    const int b = blockIdx.x;
    if (b < 128) {                       // ---- prep X: QN rows, 8 lanes/row
        int tid  = b * 256 + threadIdx.x;
        int row  = tid >> 3;
        int part = tid & 7;
        const float4 v = ((const float4*)X)[row * 8 + part];
        float nrm = v.x * v.x + v.y * v.y + v.z * v.z + v.w * v.w;
        nrm += __shfl_xor(nrm, 1);
        nrm += __shfl_xor(nrm, 2);
        nrm += __shfl_xor(nrm, 4);
        half4v h = { (_Float16)(v.x * LOG2E), (_Float16)(v.y * LOG2E),
                     (_Float16)(v.z * LOG2E), (_Float16)(v.w * LOG2E) };
        *(half4v*)(Xh + row * DD + part * 4) = h;
        if (part == 0) qn[row] = 0.5f * nrm;
        if (tid < QN) S[tid] = 0.f;      // fused memset
        if (tid == QN) *done = 0u;
    } else if (b < 2176) {               // ---- prep X_train: NN rows
        int tid  = (b - 128) * 256 + threadIdx.x;
        int row  = tid >> 3;
        int part = tid & 7;
        const float4 v = ((const float4*)Xt)[row * 8 + part];
        float nrm = v.x * v.x + v.y * v.y + v.z * v.z + v.w * v.w;
        nrm += __shfl_xor(nrm, 1);
        nrm += __shfl_xor(nrm, 2);
        nrm += __shfl_xor(nrm, 4);
        half4v h = { (_Float16)v.x, (_Float16)v.y, (_Float16)v.z, (_Float16)v.w };
        *(half4v*)(Xth + row * DD + part * 4) = h;
        if (part == 0)
            c[row] = w[row] * __builtin_amdgcn_exp2f(-0.5f * LOG2E * nrm);
    } else {                             // ---- sum(w) partials: 64 blocks
        int bid = b - 2176;
        float v = 0.f;
        for (int i = bid * 256 + threadIdx.x; i < NN; i += 64 * 256)
            v += w[i];
        #pragma unroll
        for (int o = 1; o < 64; o <<= 1) v += __shfl_xor(v, o);
        __shared__ float red[4];
        if ((threadIdx.x & 63) == 0) red[threadIdx.x >> 6] = v;
        __syncthreads();
        if (threadIdx.x == 0) swp[bid] = red[0] + red[1] + red[2] + red[3];
    }
}

// Main fused kernel: per wave, 128 queries (8 MFMA tiles) x strip of 256
// train points. Grid (8, 256), block 256 = 4 waves. Last block to finish
// also computes the final log-normalized output.
__global__ __launch_bounds__(256) void kde_main(
    const _Float16* __restrict__ Xh, const _Float16* __restrict__ Xth,
    const float* __restrict__ c, float* __restrict__ S,
    const float* __restrict__ qn, const float* __restrict__ swp,
    unsigned* __restrict__ done, float* __restrict__ out) {
    const int lane   = threadIdx.x & 63;
    const int wave   = threadIdx.x >> 6;
    const int quad   = lane >> 4;
    const int l16    = lane & 15;
    const int m_base = blockIdx.x * 512 + wave * 128;
    const int n_beg  = blockIdx.y * STRIP;

    // A fragments: 8 tiles of 16 queries, resident for the whole strip.
    // A[m = lane&15][k = quad*8 + j], j contiguous -> one 16B load each.
    half8 a[8];
    #pragma unroll
    for (int t = 0; t < 8; ++t)
        a[t] = *(const half8*)(Xh + (m_base + t * 16 + l16) * DD + quad * 8);

    float s[8][4] = {};
    const floatx4 zero = {0.f, 0.f, 0.f, 0.f};

    // Software-pipelined B/c loads (prefetch distance 1). The final prefetch
    // over-reads one tile past the strip; for the last strip that lands in
    // the adjacent workspace region (c/qn) -- harmless.
    const _Float16* bp = Xth + (size_t)(n_beg + l16) * DD + quad * 8;
    const float*    cp = c + n_beg + l16;
    half8 bcur = *(const half8*)bp;
    float ccur = *cp;

    for (int it = 0; it < ITERS; ++it) {
        bp += 16 * DD;
        cp += 16;
        half8 bnext = *(const half8*)bp;   // prefetch next tile
        float cnext = *cp;
        #pragma unroll
        for (int t = 0; t < 8; ++t) {
            floatx4 g = __builtin_amdgcn_mfma_f32_16x16x32_f16(a[t], bcur, zero, 0, 0, 0);
            #pragma unroll
            for (int r = 0; r < 4; ++r)
                s[t][r] += ccur * __builtin_amdgcn_exp2f(g[r]);  // g in log2 units
        }
        bcur = bnext;
        ccur = cnext;
    }

    // Reduce over the 16 columns (lanes sharing the same quad), then atomic.
    #pragma unroll
    for (int t = 0; t < 8; ++t) {
        #pragma unroll
        for (int r = 0; r < 4; ++r) {
            float v = s[t][r];
            v += __shfl_xor(v, 1);
            v += __shfl_xor(v, 2);
            v += __shfl_xor(v, 4);
            v += __shfl_xor(v, 8);
            if (l16 == 0)
                atomicAdd(&S[m_base + t * 16 + quad * 4 + r], v);
        }
    }

    // -------- fused finalize: last block to retire does the epilogue -------
    __threadfence();
    __shared__ int last;
    if (threadIdx.x == 0) {
        unsigned cnt = atomicAdd(done, 1u);
        last = (cnt == NBLK - 1) ? 1 : 0;
    }
    __syncthreads();
    if (last) {
        __threadfence();
        float sw = 0.f;                      // 64 partials from prep_all
        #pragma unroll
        for (int k = 0; k < 64; ++k) sw += swp[k];
        float lsw = logf(sw);
        for (int i = threadIdx.x; i < QN; i += 256) {
            float Sv = __hip_atomic_load(&S[i], __ATOMIC_RELAXED,
                                         __HIP_MEMORY_SCOPE_AGENT);
            out[i] = logf(Sv) - qn[i] - HALF_D_LOG_2PI - lsw;
        }
    }
}

extern "C" void kernel_launch(void* const* d_in, const int* in_sizes, int n_in,
                              void* d_out, int out_size, void* d_ws, size_t ws_size,
                              hipStream_t stream) {
    const float* X  = (const float*)d_in[0];
    const float* Xt = (const float*)d_in[1];
    const float* w  = (const float*)d_in[2];
    float* out = (float*)d_out;

    char* ws = (char*)d_ws;
    _Float16* Xh   = (_Float16*)(ws);
    _Float16* Xth  = (_Float16*)(ws + 262144);
    float*    c    = (float*)(ws + 4456448);
    float*    qn   = (float*)(ws + 4718592);
    float*    S    = (float*)(ws + 4734976);
    float*    swp  = (float*)(ws + 4751360);
    unsigned* done = (unsigned*)(ws + 4751616);

    prep_all<<<2240, 256, 0, stream>>>(X, Xt, w, Xh, qn, Xth, c, S, swp, done);
    kde_main<<<dim3(GRID_X, GRID_Y), 256, 0, stream>>>(Xh, Xth, c, S, qn, swp,
                                                       done, out);
}

// Round 4
// 118.409 us; speedup vs baseline: 2.0767x; 2.0767x over previous
//
#include <hip/hip_runtime.h>
#include <math.h>

// Problem constants (fixed by the reference): Q=4096 queries, N=65536 train, D=32.
#define QN 4096
#define NN 65536
#define DD 32

typedef __attribute__((ext_vector_type(8))) _Float16 half8;
typedef __attribute__((ext_vector_type(4))) _Float16 half4v;
typedef __attribute__((ext_vector_type(4))) float floatx4;

#define LOG2E 1.4426950408889634f
#define HALF_D_LOG_2PI 29.40603306254953f   // 16 * ln(2*pi)

// ---------------------------------------------------------------------------
// Workspace layout (bytes):
//   Xh    @ 0        : QN*DD*2 = 262144   (_Float16, X * log2(e))
//   Xth   @ 262144   : NN*DD*2 = 4194304  (_Float16, X_train unscaled)
//   c     @ 4456448  : NN*4    = 262144   (w_j * exp(-||y_j||^2/2))
//   qn    @ 4718592  : QN*4    = 16384    (||x_i||^2 / 2, nat units)
//   S     @ 4734976  : QN*4    = 16384    (accumulators; memset 0 each call)
//   sumw  @ 4751360  : 4
// ---------------------------------------------------------------------------

// Fused prep: blocks [0,128) convert X, [128,2176) convert X_train + c,
// [2176,2240) reduce sum(w).
__global__ __launch_bounds__(256) void prep_all(
    const float* __restrict__ X, const float* __restrict__ Xt,
    const float* __restrict__ w, _Float16* __restrict__ Xh,
    float* __restrict__ qn, _Float16* __restrict__ Xth,
    float* __restrict__ c, float* __restrict__ sumw) {
    const int b = blockIdx.x;
    if (b < 128) {                       // ---- prep X: QN rows, 8 lanes/row
        int tid  = b * 256 + threadIdx.x;
        int row  = tid >> 3;
        int part = tid & 7;
        const float4 v = ((const float4*)X)[row * 8 + part];
        float nrm = v.x * v.x + v.y * v.y + v.z * v.z + v.w * v.w;
        nrm += __shfl_xor(nrm, 1);
        nrm += __shfl_xor(nrm, 2);
        nrm += __shfl_xor(nrm, 4);
        half4v h = { (_Float16)(v.x * LOG2E), (_Float16)(v.y * LOG2E),
                     (_Float16)(v.z * LOG2E), (_Float16)(v.w * LOG2E) };
        *(half4v*)(Xh + row * DD + part * 4) = h;
        if (part == 0) qn[row] = 0.5f * nrm;
    } else if (b < 2176) {               // ---- prep X_train: NN rows
        int tid  = (b - 128) * 256 + threadIdx.x;
        int row  = tid >> 3;
        int part = tid & 7;
        const float4 v = ((const float4*)Xt)[row * 8 + part];
        float nrm = v.x * v.x + v.y * v.y + v.z * v.z + v.w * v.w;
        nrm += __shfl_xor(nrm, 1);
        nrm += __shfl_xor(nrm, 2);
        nrm += __shfl_xor(nrm, 4);
        half4v h = { (_Float16)v.x, (_Float16)v.y, (_Float16)v.z, (_Float16)v.w };
        *(half4v*)(Xth + row * DD + part * 4) = h;
        if (part == 0)
            c[row] = w[row] * __builtin_amdgcn_exp2f(-0.5f * LOG2E * nrm);
    } else {                             // ---- sum(w): 64 blocks
        int bid = b - 2176;
        float v = 0.f;
        for (int i = bid * 256 + threadIdx.x; i < NN; i += 64 * 256)
            v += w[i];
        #pragma unroll
        for (int o = 1; o < 64; o <<= 1) v += __shfl_xor(v, o);
        __shared__ float red[4];
        if ((threadIdx.x & 63) == 0) red[threadIdx.x >> 6] = v;
        __syncthreads();
        if (threadIdx.x == 0) atomicAdd(sumw, red[0] + red[1] + red[2] + red[3]);
    }
}

// Main fused kernel: per wave, 64 queries x strip of 512 train points,
// n-loop unrolled x2 (two independent B fragments in flight -> 8 parallel
// MFMA->exp chains). Grid: (QN/256, 128). Block: 256 threads = 4 waves.
__global__ __launch_bounds__(256) void kde_main(
    const _Float16* __restrict__ Xh, const _Float16* __restrict__ Xth,
    const float* __restrict__ c, float* __restrict__ S) {
    const int lane   = threadIdx.x & 63;
    const int wave   = threadIdx.x >> 6;
    const int quad   = lane >> 4;
    const int l16    = lane & 15;
    const int m_base = blockIdx.x * 256 + wave * 64;
    const int n_beg  = blockIdx.y * 512;

    // A fragments: 4 tiles of 16 queries, resident for the whole strip.
    // A[m = lane&15][k = quad*8 + j], j contiguous -> one 16B load each.
    half8 a0 = *(const half8*)(Xh + (m_base +  0 + l16) * DD + quad * 8);
    half8 a1 = *(const half8*)(Xh + (m_base + 16 + l16) * DD + quad * 8);
    half8 a2 = *(const half8*)(Xh + (m_base + 32 + l16) * DD + quad * 8);
    half8 a3 = *(const half8*)(Xh + (m_base + 48 + l16) * DD + quad * 8);

    float s0[4][4] = {};
    float s1[4][4] = {};
    const floatx4 zero = {0.f, 0.f, 0.f, 0.f};

    const _Float16* bp = Xth + (size_t)(n_beg + l16) * DD + quad * 8;
    const float*    cp = c + n_beg + l16;

    for (int it = 0; it < 16; ++it) {
        // Two independent B tiles per iteration.
        half8 b0 = *(const half8*)bp;
        half8 b1 = *(const half8*)(bp + 16 * DD);
        float c0 = cp[0];
        float c1 = cp[16];
        bp += 32 * DD;
        cp += 32;

        floatx4 g00 = __builtin_amdgcn_mfma_f32_16x16x32_f16(a0, b0, zero, 0, 0, 0);
        floatx4 g10 = __builtin_amdgcn_mfma_f32_16x16x32_f16(a0, b1, zero, 0, 0, 0);
        floatx4 g01 = __builtin_amdgcn_mfma_f32_16x16x32_f16(a1, b0, zero, 0, 0, 0);
        floatx4 g11 = __builtin_amdgcn_mfma_f32_16x16x32_f16(a1, b1, zero, 0, 0, 0);
        floatx4 g02 = __builtin_amdgcn_mfma_f32_16x16x32_f16(a2, b0, zero, 0, 0, 0);
        floatx4 g12 = __builtin_amdgcn_mfma_f32_16x16x32_f16(a2, b1, zero, 0, 0, 0);
        floatx4 g03 = __builtin_amdgcn_mfma_f32_16x16x32_f16(a3, b0, zero, 0, 0, 0);
        floatx4 g13 = __builtin_amdgcn_mfma_f32_16x16x32_f16(a3, b1, zero, 0, 0, 0);

        #pragma unroll
        for (int r = 0; r < 4; ++r) {
            s0[0][r] += c0 * __builtin_amdgcn_exp2f(g00[r]);
            s1[0][r] += c1 * __builtin_amdgcn_exp2f(g10[r]);
            s0[1][r] += c0 * __builtin_amdgcn_exp2f(g01[r]);
            s1[1][r] += c1 * __builtin_amdgcn_exp2f(g11[r]);
            s0[2][r] += c0 * __builtin_amdgcn_exp2f(g02[r]);
            s1[2][r] += c1 * __builtin_amdgcn_exp2f(g12[r]);
            s0[3][r] += c0 * __builtin_amdgcn_exp2f(g03[r]);
            s1[3][r] += c1 * __builtin_amdgcn_exp2f(g13[r]);
        }
    }

    // Reduce over the 16 columns (lanes sharing the same quad), then atomic.
    #pragma unroll
    for (int t = 0; t < 4; ++t) {
        #pragma unroll
        for (int r = 0; r < 4; ++r) {
            float v = s0[t][r] + s1[t][r];
            v += __shfl_xor(v, 1);
            v += __shfl_xor(v, 2);
            v += __shfl_xor(v, 4);
            v += __shfl_xor(v, 8);
            if (l16 == 0)
                atomicAdd(&S[m_base + t * 16 + quad * 4 + r], v);
        }
    }
}

__global__ void finalize(const float* __restrict__ S, const float* __restrict__ qn,
                         const float* __restrict__ sumw, float* __restrict__ out) {
    int i = blockIdx.x * blockDim.x + threadIdx.x;
    out[i] = logf(S[i]) - qn[i] - HALF_D_LOG_2PI - logf(*sumw);
}

extern "C" void kernel_launch(void* const* d_in, const int* in_sizes, int n_in,
                              void* d_out, int out_size, void* d_ws, size_t ws_size,
                              hipStream_t stream) {
    const float* X  = (const float*)d_in[0];
    const float* Xt = (const float*)d_in[1];
    const float* w  = (const float*)d_in[2];
    float* out = (float*)d_out;

    char* ws = (char*)d_ws;
    _Float16* Xh   = (_Float16*)(ws);
    _Float16* Xth  = (_Float16*)(ws + 262144);
    float*    c    = (float*)(ws + 4456448);
    float*    qn   = (float*)(ws + 4718592);
    float*    S    = (float*)(ws + 4734976);
    float*    sumw = (float*)(ws + 4751360);

    // Zero S + sumw (contiguous) — ws is poisoned 0xAA before each timed call.
    hipMemsetAsync(S, 0, QN * sizeof(float) + sizeof(float), stream);

    prep_all<<<2240, 256, 0, stream>>>(X, Xt, w, Xh, qn, Xth, c, sumw);
    kde_main<<<dim3(QN / 256, 128), 256, 0, stream>>>(Xh, Xth, c, S);
    finalize<<<QN / 256, 256, 0, stream>>>(S, qn, sumw, out);
}